// Round 7
// baseline (281.370 us; speedup 1.0000x reference)
//
#include <hip/hip_runtime.h>

namespace {

constexpr int kE  = 1024;
constexpr int kH  = 16;
constexpr int kR  = 256;
constexpr int kHD = 64;
constexpr int kB  = 2;
constexpr int kS  = 2048;
constexpr int kM  = kB * kS;   // 4096

typedef float  floatx4 __attribute__((ext_vector_type(4)));
typedef short  short8  __attribute__((ext_vector_type(8)));
typedef short  short4  __attribute__((ext_vector_type(4)));
typedef unsigned int uint2v __attribute__((ext_vector_type(2)));

__device__ inline short f2bf(float f) {
  union { float f; unsigned u; } x{f};
  unsigned r = x.u + 0x7FFF + ((x.u >> 16) & 1);   // RNE
  return (short)(r >> 16);
}

// packed f32x2 -> bf16x2 (RNE), one VALU instruction on gfx950
__device__ inline unsigned cvt_pk_bf16(float a, float b) {
#if defined(__HIP_DEVICE_COMPILE__)
  unsigned r;
  asm("v_cvt_pk_bf16_f32 %0, %1, %2" : "=v"(r) : "v"(a), "v"(b));
  return r;
#else
  return (unsigned)(unsigned short)f2bf(a) | ((unsigned)(unsigned short)f2bf(b) << 16);
#endif
}

__device__ inline short4 pack2(unsigned a, unsigned b) {
  union { uint2v u; short4 s; } x;
  x.u[0] = a; x.u[1] = b;
  return x.s;
}

// raw v_exp_f32 (2^x) — softmax runs in log2 domain (log2e folded into Q scale)
__device__ inline float fexp2(float x) {
#if defined(__HIP_DEVICE_COMPILE__) && __has_builtin(__builtin_amdgcn_exp2f)
  return __builtin_amdgcn_exp2f(x);
#else
  return exp2f(x);
#endif
}

// async global->LDS, 16B per lane. LDS dest = wave-uniform base + lane*16.
__device__ inline void async_copy16(const void* g, void* l) {
  __builtin_amdgcn_global_load_lds(
      (const __attribute__((address_space(1))) unsigned int*)g,
      (__attribute__((address_space(3))) unsigned int*)l,
      16, 0, 0);
}

// XCD-chunk swizzle (bijective for nwg=256, 8 XCDs): each XCD owns a
// contiguous chunk of 32 tiles -> row-panel reuse stays within one L2.
__device__ inline int xcd_swz256(int bid) {
  return ((bid & 7) << 5) | (bid >> 3);
}

// 16x16x16 bf16 MFMA (A/B = 4 bf16 in 2 VGPRs). __has_builtin is FALSE on the
// host pass of the HIP TU -> must guard with __HIP_DEVICE_COMPILE__ and give
// the host a parse-only stub (device pass verified working in round 3).
#if defined(__HIP_DEVICE_COMPILE__)
  #if __has_builtin(__builtin_amdgcn_mfma_f32_16x16x16bf16_1k)
    #define MFMA16(a, b, c) __builtin_amdgcn_mfma_f32_16x16x16bf16_1k(a, b, c, 0, 0, 0)
  #elif __has_builtin(__builtin_amdgcn_mfma_f32_16x16x16_bf16)
    #define MFMA16(a, b, c) __builtin_amdgcn_mfma_f32_16x16x16_bf16(a, b, c, 0, 0, 0)
  #else
    #error "no 16x16x16 bf16 MFMA builtin on device"
  #endif
#else
  #define MFMA16(a, b, c) (c)   // host pass: never executed
#endif

// ---------------------------------------------------------------------------
// Weight prep: fp32 Whi (256,1024) row-major -> bf16 Whi^T (1024,256).
// 4 hi weights (q,k,v,o). grid (64, 4).
// ---------------------------------------------------------------------------
struct PrepArgs { const float* src[4]; short* dst[4]; };

__global__ __launch_bounds__(256) void prep_weights(PrepArgs pa) {
  const int id = blockIdx.y;
  constexpr int K = 256, N = 1024;
  constexpr int tiles_k = K >> 6;            // 4
  const int k0 = (blockIdx.x % tiles_k) * 64;
  const int n0 = (blockIdx.x / tiles_k) * 64;
  const float* src = pa.src[id];
  short* dst = pa.dst[id];

  __shared__ float tile[64][68];
  const int t  = threadIdx.x;
  const int c4 = (t & 15) * 4;
  const int r  = t >> 4;

#pragma unroll
  for (int i = 0; i < 4; ++i) {
    const int rk = r + i * 16;
    *(float4*)&tile[rk][c4] = *(const float4*)&src[(size_t)(k0 + rk) * N + n0 + c4];
  }
  __syncthreads();
#pragma unroll
  for (int i = 0; i < 4; ++i) {
    const int rn = r + i * 16;
    short4 o = { f2bf(tile[c4 + 0][rn]), f2bf(tile[c4 + 1][rn]),
                 f2bf(tile[c4 + 2][rn]), f2bf(tile[c4 + 3][rn]) };
    *(short4*)&dst[(size_t)(n0 + rn) * K + k0 + c4] = o;
  }
}

// ---------------------------------------------------------------------------
// Aux prep: y=0..3 -> Wlo[y] fp32 (1024,256) -> bf16 same layout (128 blocks).
// y==4, bx<16 -> composite bias cb[i][n] = sum_r blo[r]*Whi[r][n] + bhi[n]
//               (i=bx>>2, n=(bx&3)*256+t; lane reads of Whi row-coalesced).
// y==4, bx==16 -> zero the 1024-float zero-bias vector.
// ---------------------------------------------------------------------------
struct AuxArgs {
  const float* wlo[4]; const float* blo[4];
  const float* whi[4]; const float* bhi[4];
  short* wloF; float* cb; float* zb;
};

__global__ __launch_bounds__(256) void aux_prep(AuxArgs a) {
  const int y = blockIdx.y, bx = blockIdx.x, t = threadIdx.x;
  if (y < 4) {
    const float* s = a.wlo[y];
    short* d = a.wloF + (size_t)y * (kE * kR);
    const size_t i = ((size_t)bx * 256 + t) * 8;   // 128 blocks * 2048 = 256K
    float4 p = *(const float4*)(s + i);
    float4 q = *(const float4*)(s + i + 4);
    short8 o = { f2bf(p.x), f2bf(p.y), f2bf(p.z), f2bf(p.w),
                 f2bf(q.x), f2bf(q.y), f2bf(q.z), f2bf(q.w) };
    *(short8*)(d + i) = o;
  } else if (bx < 16) {
    const int i = bx >> 2;
    const int n = ((bx & 3) << 8) + t;
    const float* blo = a.blo[i];
    const float* whi = a.whi[i];
    float s = a.bhi[i][n];
    for (int r = 0; r < 256; ++r) s += blo[r] * whi[r * 1024 + n];
    a.cb[i * 1024 + n] = s;
  } else if (bx == 16) {
    for (int j = t; j < 1024; j += 256) a.zb[j] = 0.f;
  }
}

// ---------------------------------------------------------------------------
// q/k/v fp32 -> bf16 row-major. 8 elements per thread. [round-1 verified]
// ---------------------------------------------------------------------------
__global__ __launch_bounds__(256) void convert_in(
    const float* q, const float* k, const float* v,
    short* xq, short* xk, short* xv)
{
  const float* srcs[3] = {q, k, v};
  short* dsts[3] = {xq, xk, xv};
  const float* s = srcs[blockIdx.y];
  short* d = dsts[blockIdx.y];
  const size_t i = ((size_t)blockIdx.x * 256 + threadIdx.x) * 8;
  float4 a = *(const float4*)(s + i);
  float4 b = *(const float4*)(s + i + 4);
  short8 o = { f2bf(a.x), f2bf(a.y), f2bf(a.z), f2bf(a.w),
               f2bf(b.x), f2bf(b.y), f2bf(b.z), f2bf(b.w) };
  *(short8*)(d + i) = o;
}

// ---------------------------------------------------------------------------
// bf16 MFMA GEMM, NT form: C[M,N] = A[M,K] @ Bt[N,K]^T + bias.
// MODE 0: bf16 row-major out.
// MODE 1: bf16 out in attention layouts (requires M=4096): z<2 -> head-major
//         (b*H+h, s, d); z==2 -> head-major transposed (b*H+h, d, s).
// MODE 2: fp32 row-major out.
// All instantiations have (M/BM)*(N/BN) == 256 -> XCD-chunk swizzle applies.
// ---------------------------------------------------------------------------
struct GemmArgs {
  const short* A[4]; const short* Bt[4]; const float* bias[4];
  void* C[4]; float scale[4];
};

template <int M, int N, int K, int BM, int BN, int MODE>
__global__ __launch_bounds__(256) void gemm_bf16(GemmArgs args) {
  constexpr int TILES_N = N / BN;
  constexpr int WTM = BM / 2, WTN = BN / 2;
  constexpr int FI = WTM / 16, FJ = WTN / 16;
  constexpr int AROUNDS = (BM * 64) / 4096;
  constexpr int BROUNDS = (BN * 64) / 4096;
  static_assert((M / BM) * (N / BN) == 256, "swizzle assumes nwg=256");
  static_assert(MODE != 1 || M == kM, "MODE1 decode assumes M=4096");

  const int z = blockIdx.y;
  const int swz = xcd_swz256(blockIdx.x);
  const int row0 = (swz / TILES_N) * BM;
  const int col0 = (swz % TILES_N) * BN;
  const short* A  = args.A[z];
  const short* Bt = args.Bt[z];
  const float* bias = args.bias[z];
  const float scale = args.scale[z];

  __shared__ short As[BM * 32];
  __shared__ short Bs[BN * 32];

  const int t    = threadIdx.x;
  const int wave = t >> 6;
  const int lane = t & 63;
  const int lq   = lane & 15;
  const int quad = lane >> 4;
  const int wm0  = (wave >> 1) * WTM;
  const int wn0  = (wave & 1) * WTN;

  const int srow = t >> 2;
  const int scol = (t & 3) * 8;

  floatx4 acc[FI][FJ] = {};

  for (int kk = 0; kk < K; kk += 32) {
#pragma unroll
    for (int r = 0; r < AROUNDS; ++r)
      async_copy16(A + (size_t)(row0 + r * 64 + srow) * K + kk + scol,
                   (char*)As + r * 4096 + wave * 1024);
#pragma unroll
    for (int r = 0; r < BROUNDS; ++r)
      async_copy16(Bt + (size_t)(col0 + r * 64 + srow) * K + kk + scol,
                   (char*)Bs + r * 4096 + wave * 1024);
    __syncthreads();

    short8 af[FI], bf[FJ];
#pragma unroll
    for (int i = 0; i < FI; ++i)
      af[i] = *(const short8*)((const char*)As + ((wm0 + i * 16 + lq) * 64 + quad * 16));
#pragma unroll
    for (int j = 0; j < FJ; ++j)
      bf[j] = *(const short8*)((const char*)Bs + ((wn0 + j * 16 + lq) * 64 + quad * 16));
#pragma unroll
    for (int i = 0; i < FI; ++i)
#pragma unroll
      for (int j = 0; j < FJ; ++j)
        acc[i][j] = __builtin_amdgcn_mfma_f32_16x16x32_bf16(af[i], bf[j], acc[i][j], 0, 0, 0);
    __syncthreads();
  }

#pragma unroll
  for (int i = 0; i < FI; ++i) {
    const int rbase = row0 + wm0 + i * 16 + quad * 4;
#pragma unroll
    for (int j = 0; j < FJ; ++j) {
      const int col = col0 + wn0 + j * 16 + lq;
      const float bj = bias[col];
      if (MODE == 2) {
        float* C = (float*)args.C[z];
#pragma unroll
        for (int r = 0; r < 4; ++r)
          C[(size_t)(rbase + r) * N + col] = (acc[i][j][r] + bj) * scale;
      } else if (MODE == 1) {
        short* C = (short*)args.C[z];
        const int h = col >> 6, d = col & 63;
        const int b = rbase >> 11, s = rbase & 2047;
        if (z == 2) {
          // V^T head-major: (bh, d, s); 4 consecutive s
          short4 o = { f2bf(acc[i][j][0] + bj), f2bf(acc[i][j][1] + bj),
                       f2bf(acc[i][j][2] + bj), f2bf(acc[i][j][3] + bj) };
          *(short4*)&C[((size_t)((b * 16 + h) * 64 + d)) * 2048 + s] = o;
        } else {
          // Q/K head-major: (bh, s, d)
#pragma unroll
          for (int r = 0; r < 4; ++r)
            C[((size_t)((b * 16 + h) * 2048 + s + r)) * 64 + d] =
                f2bf((acc[i][j][r] + bj) * scale);
        }
      } else {
        short* C = (short*)args.C[z];
#pragma unroll
        for (int r = 0; r < 4; ++r)
          C[(size_t)(rbase + r) * N + col] = f2bf((acc[i][j][r] + bj) * scale);
      }
    }
  }
}

// ---------------------------------------------------------------------------
// Flash attention, bf16 MFMA, log2-domain softmax.  [ROUND-1 VERIFIED SOURCE
// — byte-identical; do not modify: three restructures (key-split x2, 64-row
// deflation) all failed verification despite per-row-equivalent math.]
// Block = 4 waves, 128 q-rows (32/wave as 2 q-tiles). Per 64-key chunk:
// K (64x64) and V^T (64x64) staged ONCE into padded LDS; the K/V LDS
// fragments are reused across both q-tiles (halves LDS+staging per q).
// S^T = K @ Q^T; P stays in registers; O^T += V^T @ P^T.
// Softmax diet: exp2 (log2e pre-folded into Q scale), v_cvt_pk_bf16_f32 for
// P->bf16, defer-max (skip rescale while chunk max <= m + 10 in log2 units).
// ---------------------------------------------------------------------------
__global__ __launch_bounds__(256) void attn_mfma(
    const short* __restrict__ Qp, const short* __restrict__ Kp,
    const short* __restrict__ Vtp, short* __restrict__ O)
{
  __shared__ short Ks[64][72];   // [local key][d], pad 72 (144B rows, 16B-aligned)
  __shared__ short Vs[64][72];   // [d][local key]

  const int t    = threadIdx.x;
  const int wave = t >> 6;
  const int lane = t & 63;
  const int lq   = lane & 15;
  const int quad = lane >> 4;

  const int q0 = blockIdx.x * 128;
  const int bh = blockIdx.y;
  const int b  = bh >> 4;
  const int h  = bh & 15;

  // Q fragments (head-major (bh,s,d)): n=q=lq, k=d. Two q-tiles per wave.
  short8 qf0[2], qf1[2];
#pragma unroll
  for (int qt = 0; qt < 2; ++qt) {
    const short* qrow = Qp + ((size_t)bh * kS + q0 + wave * 32 + qt * 16 + lq) * 64;
    qf0[qt] = *(const short8*)(qrow + quad * 8);
    qf1[qt] = *(const short8*)(qrow + 32 + quad * 8);
  }

  const short* Kbase = Kp  + (size_t)bh * kS * 64;   // (s, d) rows of 128B
  const short* Vbase = Vtp + (size_t)bh * 64 * kS;   // (d, s) rows of 4KB

  // staging: wave w covers rows w*16 .. w*16+15 via two 8-row coalesced loads
  const int srow = wave * 16 + (lane >> 3);
  const int scol = (lane & 7) * 8;

  floatx4 Oacc[4][2] = {};
  float m[2] = {-1e30f, -1e30f};
  float l[2] = {0.f, 0.f};

  short8 gk0 = *(const short8*)(Kbase + (size_t)(srow) * 64 + scol);
  short8 gk1 = *(const short8*)(Kbase + (size_t)(srow + 8) * 64 + scol);
  short8 gv0 = *(const short8*)(Vbase + (size_t)srow * kS + scol);
  short8 gv1 = *(const short8*)(Vbase + (size_t)(srow + 8) * kS + scol);

  for (int kc = 0; kc < kS; kc += 64) {
    __syncthreads();                      // previous chunk's reads done
    *(short8*)&Ks[srow][scol]     = gk0;
    *(short8*)&Ks[srow + 8][scol] = gk1;
    *(short8*)&Vs[srow][scol]     = gv0;
    *(short8*)&Vs[srow + 8][scol] = gv1;
    __syncthreads();                      // tiles visible

    if (kc + 64 < kS) {                   // prefetch next chunk (hidden by compute)
      gk0 = *(const short8*)(Kbase + (size_t)(kc + 64 + srow) * 64 + scol);
      gk1 = *(const short8*)(Kbase + (size_t)(kc + 64 + srow + 8) * 64 + scol);
      gv0 = *(const short8*)(Vbase + (size_t)srow * kS + kc + 64 + scol);
      gv1 = *(const short8*)(Vbase + (size_t)(srow + 8) * kS + kc + 64 + scol);
    }

    // ---- scores: S^T tiles (key16 x q16), A = K rows from LDS (shared by qt) ----
    floatx4 Sc[4][2];
#pragma unroll
    for (int tt = 0; tt < 4; ++tt) {
      short8 a0 = *(const short8*)&Ks[tt * 16 + lq][quad * 8];
      short8 a1 = *(const short8*)&Ks[tt * 16 + lq][32 + quad * 8];
#pragma unroll
      for (int qt = 0; qt < 2; ++qt) {
        floatx4 c = {};
        c = __builtin_amdgcn_mfma_f32_16x16x32_bf16(a0, qf0[qt], c, 0, 0, 0);
        c = __builtin_amdgcn_mfma_f32_16x16x32_bf16(a1, qf1[qt], c, 0, 0, 0);
        Sc[tt][qt] = c;
      }
    }

    // ---- online softmax (log2 domain), per q-tile ----
    short4 pf[4][2];
#pragma unroll
    for (int qt = 0; qt < 2; ++qt) {
      float x0 = fmaxf(fmaxf(Sc[0][qt][0], Sc[0][qt][1]), fmaxf(Sc[0][qt][2], Sc[0][qt][3]));
      float x1 = fmaxf(fmaxf(Sc[1][qt][0], Sc[1][qt][1]), fmaxf(Sc[1][qt][2], Sc[1][qt][3]));
      float x2 = fmaxf(fmaxf(Sc[2][qt][0], Sc[2][qt][1]), fmaxf(Sc[2][qt][2], Sc[2][qt][3]));
      float x3 = fmaxf(fmaxf(Sc[3][qt][0], Sc[3][qt][1]), fmaxf(Sc[3][qt][2], Sc[3][qt][3]));
      float plane = fmaxf(fmaxf(x0, x1), fmaxf(x2, x3));

      // defer-max: only rescale when this chunk's max grew past m+10 (log2);
      // otherwise P is bounded by 2^10 which fp32 accum / bf16 handle fine.
      if (!__all(plane <= m[qt] + 10.f)) {
        float mc = fmaxf(plane, __shfl_xor(plane, 16, 64));
        mc = fmaxf(mc, __shfl_xor(mc, 32, 64));
        const float mn = fmaxf(m[qt], mc);
        const float a = fexp2(m[qt] - mn);
        m[qt] = mn;
        l[qt] *= a;
#pragma unroll
        for (int dt = 0; dt < 4; ++dt) Oacc[dt][qt] *= a;
      }

      float ls = 0.f;
#pragma unroll
      for (int tt = 0; tt < 4; ++tt) {
        float p0 = fexp2(Sc[tt][qt][0] - m[qt]);
        float p1 = fexp2(Sc[tt][qt][1] - m[qt]);
        float p2 = fexp2(Sc[tt][qt][2] - m[qt]);
        float p3 = fexp2(Sc[tt][qt][3] - m[qt]);
        ls += (p0 + p1) + (p2 + p3);
        pf[tt][qt] = pack2(cvt_pk_bf16(p0, p1), cvt_pk_bf16(p2, p3));
      }
      l[qt] += ls;
    }

    // ---- PV: O^T += V^T @ P^T, A = V^T rows from LDS (shared by qt) ----
#pragma unroll
    for (int dt = 0; dt < 4; ++dt) {
#pragma unroll
      for (int tt = 0; tt < 4; ++tt) {
        short4 vf = *(const short4*)&Vs[dt * 16 + lq][tt * 16 + quad * 4];
#pragma unroll
        for (int qt = 0; qt < 2; ++qt)
          Oacc[dt][qt] = MFMA16(vf, pf[tt][qt], Oacc[dt][qt]);
      }
    }
  }

  // ---- epilogue ----
#pragma unroll
  for (int qt = 0; qt < 2; ++qt) {
    float lv = l[qt];
    lv += __shfl_xor(lv, 16, 64);
    lv += __shfl_xor(lv, 32, 64);
    const float inv = 1.f / lv;

    short* orow = O + ((size_t)(b * kS + q0 + wave * 32 + qt * 16 + lq)) * kE + h * kHD;
#pragma unroll
    for (int dt = 0; dt < 4; ++dt) {
      short4 o = pack2(cvt_pk_bf16(Oacc[dt][qt][0] * inv, Oacc[dt][qt][1] * inv),
                       cvt_pk_bf16(Oacc[dt][qt][2] * inv, Oacc[dt][qt][3] * inv));
      *(short4*)&orow[dt * 16 + quad * 4] = o;
    }
  }
}

}  // namespace

extern "C" void kernel_launch(void* const* d_in, const int* in_sizes, int n_in,
                              void* d_out, int out_size, void* d_ws, size_t ws_size,
                              hipStream_t stream) {
  // ---- workspace layout (bf16 shorts), total < 34M shorts (old footprint) --
  constexpr size_t SZ = (size_t)kM * kE;          // 4M elements
  short* ws   = (short*)d_ws;
  short* Xq   = ws;                               // 0  .. 12M: bf16 inputs
  short* Xk   = Xq  + SZ;
  short* Xv   = Xk  + SZ;
  short* Qh   = Xv  + SZ;                         // 12 .. 24M: head-major q/k/v^T
  short* Kh   = Qh  + SZ;
  short* Vth  = Kh  + SZ;
  short* Ab   = Vth + SZ;                         // 24 .. 28M: attn out (b,s,E)
  short* WloF = Ab;                               // alias: dead until attn runs
  short* WhiT = Ab  + SZ;                         // 28 .. 29M: 4 x (1024,256)
  short* Wct  = WhiT + 4 * (size_t)(kE * kR);     // 29 .. 33M: 4 x (1024,1024)
  float* cb   = (float*)(Wct + 4 * (size_t)(kE * kE));  // 4 x 1024 composite bias
  float* zb   = cb + 4 * 1024;                    // 1024 zeros

  // ---- 1. hi-weight transpose+convert: WhiT[i] ----
  {
    PrepArgs pa;
    const int whidx[4] = {5, 9, 13, 17};
    for (int i = 0; i < 4; ++i) {
      pa.src[i] = (const float*)d_in[whidx[i]];
      pa.dst[i] = WhiT + (size_t)i * (kE * kR);
    }
    prep_weights<<<dim3(64, 4), dim3(256), 0, stream>>>(pa);
  }

  // ---- 2. aux: Wlo->bf16 flat, composite biases, zero-bias ----
  {
    AuxArgs aa;
    const int wlidx[4] = {3, 7, 11, 15};
    const int blidx[4] = {4, 8, 12, 16};
    const int whidx[4] = {5, 9, 13, 17};
    const int bhidx[4] = {6, 10, 14, 18};
    for (int i = 0; i < 4; ++i) {
      aa.wlo[i] = (const float*)d_in[wlidx[i]];
      aa.blo[i] = (const float*)d_in[blidx[i]];
      aa.whi[i] = (const float*)d_in[whidx[i]];
      aa.bhi[i] = (const float*)d_in[bhidx[i]];
    }
    aa.wloF = WloF; aa.cb = cb; aa.zb = zb;
    aux_prep<<<dim3(128, 5), dim3(256), 0, stream>>>(aa);
  }

  // ---- 3. input convert ----
  convert_in<<<dim3((kM * kE) / (256 * 8), 3), dim3(256), 0, stream>>>(
      (const float*)d_in[0], (const float*)d_in[1], (const float*)d_in[2], Xq, Xk, Xv);

  // ---- 4. composite weights: Wct[i] = (Wlo_i @ Whi_i)^T, bf16 ----
  // NT form: C[m][n] = sum_r WhiT[m][r] * WloF[n][r]  ==  Wc^T[m][n].
  {
    GemmArgs ga;
    for (int i = 0; i < 4; ++i) {
      ga.A[i]    = WhiT + (size_t)i * (kE * kR);
      ga.Bt[i]   = WloF + (size_t)i * (kE * kR);
      ga.bias[i] = zb;
      ga.C[i]    = Wct + (size_t)i * (kE * kE);
      ga.scale[i] = 1.f;
    }
    gemm_bf16<kE, kE, kR, 64, 64, 0><<<dim3(256, 4), dim3(256), 0, stream>>>(ga);
  }

  // ---- 5. qkv projections (composite, K=1024) -> attention layouts ----
  {
    GemmArgs ga;
    ga.A[0] = Xq; ga.A[1] = Xk; ga.A[2] = Xv;
    for (int i = 0; i < 3; ++i) {
      ga.Bt[i]   = Wct + (size_t)i * (kE * kE);
      ga.bias[i] = cb + i * 1024;
    }
    ga.C[0] = Qh; ga.C[1] = Kh; ga.C[2] = Vth;
    // Q scale = 1/sqrt(HD) * log2(e): softmax runs in exp2/log2 domain.
    ga.scale[0] = 0.125f * 1.44269504088896340736f;
    ga.scale[1] = 1.f; ga.scale[2] = 1.f;
    gemm_bf16<kM, kE, kE, 128, 128, 1><<<dim3(256, 3), dim3(256), 0, stream>>>(ga);
  }

  // ---- 6. attention (128 q-rows per block) ----
  attn_mfma<<<dim3(kS / 128, kB * kH), dim3(256), 0, stream>>>(Qh, Kh, Vth, Ab);

  // ---- 7. output projection (composite, K=1024), fp32 out ----
  {
    GemmArgs ga;
    ga.A[0]    = Ab;
    ga.Bt[0]   = Wct + (size_t)3 * (kE * kE);
    ga.bias[0] = cb + 3 * 1024;
    ga.C[0]    = d_out;
    ga.scale[0] = 1.f;
    gemm_bf16<kM, kE, kE, 128, 128, 2><<<dim3(256, 1), dim3(256), 0, stream>>>(ga);
  }
}

// Round 8
// 243.794 us; speedup vs baseline: 1.1541x; 1.1541x over previous
//
#include <hip/hip_runtime.h>

namespace {

constexpr int kE  = 1024;
constexpr int kH  = 16;
constexpr int kR  = 256;
constexpr int kHD = 64;
constexpr int kB  = 2;
constexpr int kS  = 2048;
constexpr int kM  = kB * kS;   // 4096

typedef float  floatx4 __attribute__((ext_vector_type(4)));
typedef short  short8  __attribute__((ext_vector_type(8)));
typedef short  short4  __attribute__((ext_vector_type(4)));
typedef unsigned int uint2v __attribute__((ext_vector_type(2)));

__device__ inline short f2bf(float f) {
  union { float f; unsigned u; } x{f};
  unsigned r = x.u + 0x7FFF + ((x.u >> 16) & 1);   // RNE
  return (short)(r >> 16);
}

// packed f32x2 -> bf16x2 (RNE), one VALU instruction on gfx950
__device__ inline unsigned cvt_pk_bf16(float a, float b) {
#if defined(__HIP_DEVICE_COMPILE__)
  unsigned r;
  asm("v_cvt_pk_bf16_f32 %0, %1, %2" : "=v"(r) : "v"(a), "v"(b));
  return r;
#else
  return (unsigned)(unsigned short)f2bf(a) | ((unsigned)(unsigned short)f2bf(b) << 16);
#endif
}

__device__ inline short4 pack2(unsigned a, unsigned b) {
  union { uint2v u; short4 s; } x;
  x.u[0] = a; x.u[1] = b;
  return x.s;
}

__device__ inline short8 pack4(unsigned a, unsigned b, unsigned c, unsigned d) {
  union { unsigned u[4]; short8 s; } x;
  x.u[0] = a; x.u[1] = b; x.u[2] = c; x.u[3] = d;
  return x.s;
}

// raw v_exp_f32 (2^x) — softmax runs in log2 domain (log2e folded into Q scale)
__device__ inline float fexp2(float x) {
#if defined(__HIP_DEVICE_COMPILE__) && __has_builtin(__builtin_amdgcn_exp2f)
  return __builtin_amdgcn_exp2f(x);
#else
  return exp2f(x);
#endif
}

// XCD-chunk swizzle (bijective for nwg=256, 8 XCDs): each XCD owns a
// contiguous chunk of 32 tiles -> row-panel reuse stays within one L2.
__device__ inline int xcd_swz256(int bid) {
  return ((bid & 7) << 5) | (bid >> 3);
}

// 16x16x16 bf16 MFMA (A/B = 4 bf16 in 2 VGPRs). __has_builtin is FALSE on the
// host pass of the HIP TU -> must guard with __HIP_DEVICE_COMPILE__ and give
// the host a parse-only stub (device pass verified working in round 3).
#if defined(__HIP_DEVICE_COMPILE__)
  #if __has_builtin(__builtin_amdgcn_mfma_f32_16x16x16bf16_1k)
    #define MFMA16(a, b, c) __builtin_amdgcn_mfma_f32_16x16x16bf16_1k(a, b, c, 0, 0, 0)
  #elif __has_builtin(__builtin_amdgcn_mfma_f32_16x16x16_bf16)
    #define MFMA16(a, b, c) __builtin_amdgcn_mfma_f32_16x16x16_bf16(a, b, c, 0, 0, 0)
  #else
    #error "no 16x16x16 bf16 MFMA builtin on device"
  #endif
#else
  #define MFMA16(a, b, c) (c)   // host pass: never executed
#endif

// ---------------------------------------------------------------------------
// Weight prep: fp32 W (K,N) row-major -> bf16 W^T (N,K) row-major.
// 8 weights: even id = lo (1024,256), odd id = hi (256,1024).
// ---------------------------------------------------------------------------
struct PrepArgs { const float* src[8]; short* dst[8]; };

__global__ __launch_bounds__(256) void prep_weights(PrepArgs pa) {
  const int id = blockIdx.y;
  const bool lo = (id & 1) == 0;
  const int K = lo ? 1024 : 256;
  const int N = lo ? 256 : 1024;
  const int tiles_k = K >> 6;
  const int k0 = (blockIdx.x % tiles_k) * 64;
  const int n0 = (blockIdx.x / tiles_k) * 64;
  const float* src = pa.src[id];
  short* dst = pa.dst[id];

  __shared__ float tile[64][68];
  const int t  = threadIdx.x;
  const int c4 = (t & 15) * 4;
  const int r  = t >> 4;

#pragma unroll
  for (int i = 0; i < 4; ++i) {
    const int rk = r + i * 16;
    *(float4*)&tile[rk][c4] = *(const float4*)&src[(size_t)(k0 + rk) * N + n0 + c4];
  }
  __syncthreads();
#pragma unroll
  for (int i = 0; i < 4; ++i) {
    const int rn = r + i * 16;
    short4 o = { f2bf(tile[c4 + 0][rn]), f2bf(tile[c4 + 1][rn]),
                 f2bf(tile[c4 + 2][rn]), f2bf(tile[c4 + 3][rn]) };
    *(short4*)&dst[(size_t)(n0 + rn) * K + k0 + c4] = o;
  }
}

// ---------------------------------------------------------------------------
// bf16 MFMA GEMM, NT form: C[M,N] = A[M,K] @ Bt[N,K]^T + bias.
// DOUBLE-BUFFERED staging (attn's verified pattern): tile k+1 is loaded to
// registers while MFMA runs on tile k; LDS rows padded 64B->80B so the
// fragment ds_read_b128 is 2-way bank-aliased (free) instead of 8-way.
// MODE 0: bf16 row-major out.
// MODE 1: bf16 out in attention layouts (requires M=4096): z<2 -> head-major
//         (b*H+h, s, d); z==2 -> head-major transposed (b*H+h, d, s).
// MODE 2: fp32 row-major out.
// All instantiations have (M/BM)*(N/BN) == 256 -> XCD-chunk swizzle applies.
// ---------------------------------------------------------------------------
struct GemmArgs {
  const short* A[3]; const short* Bt[3]; const float* bias[3];
  void* C[3]; float scale[3];
};

template <int M, int N, int K, int BM, int BN, int MODE>
__global__ __launch_bounds__(256) void gemm_bf16(GemmArgs args) {
  constexpr int TILES_N = N / BN;
  constexpr int WTM = BM / 2, WTN = BN / 2;
  constexpr int FI = WTM / 16, FJ = WTN / 16;
  constexpr int AROUNDS = (BM * 64) / 4096;
  constexpr int BROUNDS = (BN * 64) / 4096;
  constexpr int P = 80;   // padded LDS row bytes (32 bf16 data + 8 pad shorts)
  static_assert((M / BM) * (N / BN) == 256, "swizzle assumes nwg=256");
  static_assert(MODE != 1 || M == kM, "MODE1 decode assumes M=4096");

  const int z = blockIdx.y;
  const int swz = xcd_swz256(blockIdx.x);
  const int row0 = (swz / TILES_N) * BM;
  const int col0 = (swz % TILES_N) * BN;
  const short* A  = args.A[z];
  const short* Bt = args.Bt[z];
  const float* bias = args.bias[z];
  const float scale = args.scale[z];

  __shared__ short As[BM * 40];
  __shared__ short Bs[BN * 40];

  const int t    = threadIdx.x;
  const int wave = t >> 6;
  const int lane = t & 63;
  const int lq   = lane & 15;
  const int quad = lane >> 4;
  const int wm0  = (wave >> 1) * WTM;
  const int wn0  = (wave & 1) * WTN;

  const int srow = t >> 2;          // staging row within a 64-row group
  const int scol = (t & 3) * 8;     // staging col (bf16 elements)
  const int sbyte = (t & 3) * 16;   // staging col (bytes)

  floatx4 acc[FI][FJ] = {};

  // prologue: tile kk=0 -> registers
  short8 ra[AROUNDS], rb[BROUNDS];
#pragma unroll
  for (int r = 0; r < AROUNDS; ++r)
    ra[r] = *(const short8*)(A + (size_t)(row0 + r * 64 + srow) * K + scol);
#pragma unroll
  for (int r = 0; r < BROUNDS; ++r)
    rb[r] = *(const short8*)(Bt + (size_t)(col0 + r * 64 + srow) * K + scol);

  for (int kk = 0; kk < K; kk += 32) {
    __syncthreads();                       // previous tile's fragment reads done
#pragma unroll
    for (int r = 0; r < AROUNDS; ++r)
      *(short8*)((char*)As + (r * 64 + srow) * P + sbyte) = ra[r];
#pragma unroll
    for (int r = 0; r < BROUNDS; ++r)
      *(short8*)((char*)Bs + (r * 64 + srow) * P + sbyte) = rb[r];
    __syncthreads();                       // tile visible

    if (kk + 32 < K) {                     // prefetch next tile (hidden by MFMA)
#pragma unroll
      for (int r = 0; r < AROUNDS; ++r)
        ra[r] = *(const short8*)(A + (size_t)(row0 + r * 64 + srow) * K + kk + 32 + scol);
#pragma unroll
      for (int r = 0; r < BROUNDS; ++r)
        rb[r] = *(const short8*)(Bt + (size_t)(col0 + r * 64 + srow) * K + kk + 32 + scol);
    }

    short8 af[FI], bf[FJ];
#pragma unroll
    for (int i = 0; i < FI; ++i)
      af[i] = *(const short8*)((const char*)As + ((wm0 + i * 16 + lq) * P + quad * 16));
#pragma unroll
    for (int j = 0; j < FJ; ++j)
      bf[j] = *(const short8*)((const char*)Bs + ((wn0 + j * 16 + lq) * P + quad * 16));
#pragma unroll
    for (int i = 0; i < FI; ++i)
#pragma unroll
      for (int j = 0; j < FJ; ++j)
        acc[i][j] = __builtin_amdgcn_mfma_f32_16x16x32_bf16(af[i], bf[j], acc[i][j], 0, 0, 0);
  }

#pragma unroll
  for (int i = 0; i < FI; ++i) {
    const int rbase = row0 + wm0 + i * 16 + quad * 4;
#pragma unroll
    for (int j = 0; j < FJ; ++j) {
      const int col = col0 + wn0 + j * 16 + lq;
      const float bj = bias[col];
      if (MODE == 2) {
        float* C = (float*)args.C[z];
#pragma unroll
        for (int r = 0; r < 4; ++r)
          C[(size_t)(rbase + r) * N + col] = (acc[i][j][r] + bj) * scale;
      } else if (MODE == 1) {
        short* C = (short*)args.C[z];
        const int h = col >> 6, d = col & 63;
        const int b = rbase >> 11, s = rbase & 2047;
        if (z == 2) {
          // V^T head-major: (bh, d, s); 4 consecutive s
          short4 o = { f2bf(acc[i][j][0] + bj), f2bf(acc[i][j][1] + bj),
                       f2bf(acc[i][j][2] + bj), f2bf(acc[i][j][3] + bj) };
          *(short4*)&C[((size_t)((b * 16 + h) * 64 + d)) * 2048 + s] = o;
        } else {
          // Q/K head-major: (bh, s, d)
#pragma unroll
          for (int r = 0; r < 4; ++r)
            C[((size_t)((b * 16 + h) * 2048 + s + r)) * 64 + d] =
                f2bf((acc[i][j][r] + bj) * scale);
        }
      } else {
        short* C = (short*)args.C[z];
#pragma unroll
        for (int r = 0; r < 4; ++r)
          C[(size_t)(rbase + r) * N + col] = f2bf((acc[i][j][r] + bj) * scale);
      }
    }
  }
}

// ---------------------------------------------------------------------------
// lo-projection GEMM with FUSED fp32->bf16 A conversion (replaces convert_in
// + bf16 lo GEMM). C[M,256] = A_f32[M,1024] @ Bt[256,1024]^T + bias, bf16
// row-major out. BM=BN=64, BK=32, 4 waves (2x2), FI=FJ=2.
// Both A and B now reg-staged double-buffered (next tile prefetched under
// MFMA); B rows padded to 80B like gemm_bf16. A conversion to bf16 happens
// in-register at fragment-read (v_cvt_pk_bf16_f32, same RNE as f2bf).
// ---------------------------------------------------------------------------
struct GemmLoArgs {
  const float* A[3]; const short* Bt[3]; const float* bias[3]; short* C[3];
};

__global__ __launch_bounds__(256) void gemm_lo_f32a(GemmLoArgs args) {
  constexpr int N = kR, K = kE, BM = 64, BN = 64;
  constexpr int TILES_N = N / BN;           // 4
  constexpr int WTM = BM / 2, WTN = BN / 2; // 32
  constexpr int FI = WTM / 16, FJ = WTN / 16;
  constexpr int P = 80;
  static_assert((kM / BM) * (N / BN) == 256, "swizzle assumes nwg=256");

  const int z = blockIdx.y;
  const int swz = xcd_swz256(blockIdx.x);
  const int row0 = (swz / TILES_N) * BM;
  const int col0 = (swz % TILES_N) * BN;
  const float* A  = args.A[z];
  const short* Bt = args.Bt[z];
  const float* bias = args.bias[z];
  short* C = args.C[z];

  __shared__ float As32[64][36];   // padded: 144B rows (16B-aligned)
  __shared__ short Bs[BN * 40];

  const int t    = threadIdx.x;
  const int wave = t >> 6;
  const int lane = t & 63;
  const int lq   = lane & 15;
  const int quad = lane >> 4;
  const int wm0  = (wave >> 1) * WTM;
  const int wn0  = (wave & 1) * WTN;

  // A staging: thread t -> row t>>2, floats (t&3)*8 .. +7 (64 rows x 32 f32)
  const int arow  = t >> 2;
  const int acolf = (t & 3) * 8;
  // B staging: row t>>2, bf16 cols (t&3)*8 .. +7
  const int srow  = t >> 2;
  const int scol  = (t & 3) * 8;
  const int sbyte = (t & 3) * 16;

  floatx4 acc[FI][FJ] = {};

  const float* arow_p = A + (size_t)(row0 + arow) * K + acolf;
  float4 ga0 = *(const float4*)(arow_p);
  float4 ga1 = *(const float4*)(arow_p + 4);
  short8 rb  = *(const short8*)(Bt + (size_t)(col0 + srow) * K + scol);

  for (int kk = 0; kk < K; kk += 32) {
    __syncthreads();                       // previous tile's fragment reads done
    *(float4*)&As32[arow][acolf]     = ga0;
    *(float4*)&As32[arow][acolf + 4] = ga1;
    *(short8*)((char*)Bs + srow * P + sbyte) = rb;
    __syncthreads();                       // tile visible

    if (kk + 32 < K) {                     // prefetch next tile (hidden by MFMA)
      ga0 = *(const float4*)(arow_p + kk + 32);
      ga1 = *(const float4*)(arow_p + kk + 36);
      rb  = *(const short8*)(Bt + (size_t)(col0 + srow) * K + kk + 32 + scol);
    }

    short8 af[FI], bf[FJ];
#pragma unroll
    for (int i = 0; i < FI; ++i) {
      const int r = wm0 + i * 16 + lq;
      float4 f0 = *(const float4*)&As32[r][quad * 8];
      float4 f1 = *(const float4*)&As32[r][quad * 8 + 4];
      af[i] = pack4(cvt_pk_bf16(f0.x, f0.y), cvt_pk_bf16(f0.z, f0.w),
                    cvt_pk_bf16(f1.x, f1.y), cvt_pk_bf16(f1.z, f1.w));
    }
#pragma unroll
    for (int j = 0; j < FJ; ++j)
      bf[j] = *(const short8*)((const char*)Bs + ((wn0 + j * 16 + lq) * P + quad * 16));
#pragma unroll
    for (int i = 0; i < FI; ++i)
#pragma unroll
      for (int j = 0; j < FJ; ++j)
        acc[i][j] = __builtin_amdgcn_mfma_f32_16x16x32_bf16(af[i], bf[j], acc[i][j], 0, 0, 0);
  }

#pragma unroll
  for (int i = 0; i < FI; ++i) {
    const int rbase = row0 + wm0 + i * 16 + quad * 4;
#pragma unroll
    for (int j = 0; j < FJ; ++j) {
      const int col = col0 + wn0 + j * 16 + lq;
      const float bj = bias[col];
#pragma unroll
      for (int r = 0; r < 4; ++r)
        C[(size_t)(rbase + r) * N + col] = f2bf(acc[i][j][r] + bj);
    }
  }
}

// ---------------------------------------------------------------------------
// Flash attention, bf16 MFMA, log2-domain softmax.  [ROUND-1 VERIFIED SOURCE
// — byte-identical; do not modify: three restructures (key-split x2, 64-row
// deflation) all failed verification despite per-row-equivalent math.]
// Block = 4 waves, 128 q-rows (32/wave as 2 q-tiles). Per 64-key chunk:
// K (64x64) and V^T (64x64) staged ONCE into padded LDS; the K/V LDS
// fragments are reused across both q-tiles (halves LDS+staging per q).
// S^T = K @ Q^T; P stays in registers; O^T += V^T @ P^T.
// Softmax diet: exp2 (log2e pre-folded into Q scale), v_cvt_pk_bf16_f32 for
// P->bf16, defer-max (skip rescale while chunk max <= m + 10 in log2 units).
// ---------------------------------------------------------------------------
__global__ __launch_bounds__(256) void attn_mfma(
    const short* __restrict__ Qp, const short* __restrict__ Kp,
    const short* __restrict__ Vtp, short* __restrict__ O)
{
  __shared__ short Ks[64][72];   // [local key][d], pad 72 (144B rows, 16B-aligned)
  __shared__ short Vs[64][72];   // [d][local key]

  const int t    = threadIdx.x;
  const int wave = t >> 6;
  const int lane = t & 63;
  const int lq   = lane & 15;
  const int quad = lane >> 4;

  const int q0 = blockIdx.x * 128;
  const int bh = blockIdx.y;
  const int b  = bh >> 4;
  const int h  = bh & 15;

  // Q fragments (head-major (bh,s,d)): n=q=lq, k=d. Two q-tiles per wave.
  short8 qf0[2], qf1[2];
#pragma unroll
  for (int qt = 0; qt < 2; ++qt) {
    const short* qrow = Qp + ((size_t)bh * kS + q0 + wave * 32 + qt * 16 + lq) * 64;
    qf0[qt] = *(const short8*)(qrow + quad * 8);
    qf1[qt] = *(const short8*)(qrow + 32 + quad * 8);
  }

  const short* Kbase = Kp  + (size_t)bh * kS * 64;   // (s, d) rows of 128B
  const short* Vbase = Vtp + (size_t)bh * 64 * kS;   // (d, s) rows of 4KB

  // staging: wave w covers rows w*16 .. w*16+15 via two 8-row coalesced loads
  const int srow = wave * 16 + (lane >> 3);
  const int scol = (lane & 7) * 8;

  floatx4 Oacc[4][2] = {};
  float m[2] = {-1e30f, -1e30f};
  float l[2] = {0.f, 0.f};

  short8 gk0 = *(const short8*)(Kbase + (size_t)(srow) * 64 + scol);
  short8 gk1 = *(const short8*)(Kbase + (size_t)(srow + 8) * 64 + scol);
  short8 gv0 = *(const short8*)(Vbase + (size_t)srow * kS + scol);
  short8 gv1 = *(const short8*)(Vbase + (size_t)(srow + 8) * kS + scol);

  for (int kc = 0; kc < kS; kc += 64) {
    __syncthreads();                      // previous chunk's reads done
    *(short8*)&Ks[srow][scol]     = gk0;
    *(short8*)&Ks[srow + 8][scol] = gk1;
    *(short8*)&Vs[srow][scol]     = gv0;
    *(short8*)&Vs[srow + 8][scol] = gv1;
    __syncthreads();                      // tiles visible

    if (kc + 64 < kS) {                   // prefetch next chunk (hidden by compute)
      gk0 = *(const short8*)(Kbase + (size_t)(kc + 64 + srow) * 64 + scol);
      gk1 = *(const short8*)(Kbase + (size_t)(kc + 64 + srow + 8) * 64 + scol);
      gv0 = *(const short8*)(Vbase + (size_t)srow * kS + kc + 64 + scol);
      gv1 = *(const short8*)(Vbase + (size_t)(srow + 8) * kS + kc + 64 + scol);
    }

    // ---- scores: S^T tiles (key16 x q16), A = K rows from LDS (shared by qt) ----
    floatx4 Sc[4][2];
#pragma unroll
    for (int tt = 0; tt < 4; ++tt) {
      short8 a0 = *(const short8*)&Ks[tt * 16 + lq][quad * 8];
      short8 a1 = *(const short8*)&Ks[tt * 16 + lq][32 + quad * 8];
#pragma unroll
      for (int qt = 0; qt < 2; ++qt) {
        floatx4 c = {};
        c = __builtin_amdgcn_mfma_f32_16x16x32_bf16(a0, qf0[qt], c, 0, 0, 0);
        c = __builtin_amdgcn_mfma_f32_16x16x32_bf16(a1, qf1[qt], c, 0, 0, 0);
        Sc[tt][qt] = c;
      }
    }

    // ---- online softmax (log2 domain), per q-tile ----
    short4 pf[4][2];
#pragma unroll
    for (int qt = 0; qt < 2; ++qt) {
      float x0 = fmaxf(fmaxf(Sc[0][qt][0], Sc[0][qt][1]), fmaxf(Sc[0][qt][2], Sc[0][qt][3]));
      float x1 = fmaxf(fmaxf(Sc[1][qt][0], Sc[1][qt][1]), fmaxf(Sc[1][qt][2], Sc[1][qt][3]));
      float x2 = fmaxf(fmaxf(Sc[2][qt][0], Sc[2][qt][1]), fmaxf(Sc[2][qt][2], Sc[2][qt][3]));
      float x3 = fmaxf(fmaxf(Sc[3][qt][0], Sc[3][qt][1]), fmaxf(Sc[3][qt][2], Sc[3][qt][3]));
      float plane = fmaxf(fmaxf(x0, x1), fmaxf(x2, x3));

      // defer-max: only rescale when this chunk's max grew past m+10 (log2);
      // otherwise P is bounded by 2^10 which fp32 accum / bf16 handle fine.
      if (!__all(plane <= m[qt] + 10.f)) {
        float mc = fmaxf(plane, __shfl_xor(plane, 16, 64));
        mc = fmaxf(mc, __shfl_xor(mc, 32, 64));
        const float mn = fmaxf(m[qt], mc);
        const float a = fexp2(m[qt] - mn);
        m[qt] = mn;
        l[qt] *= a;
#pragma unroll
        for (int dt = 0; dt < 4; ++dt) Oacc[dt][qt] *= a;
      }

      float ls = 0.f;
#pragma unroll
      for (int tt = 0; tt < 4; ++tt) {
        float p0 = fexp2(Sc[tt][qt][0] - m[qt]);
        float p1 = fexp2(Sc[tt][qt][1] - m[qt]);
        float p2 = fexp2(Sc[tt][qt][2] - m[qt]);
        float p3 = fexp2(Sc[tt][qt][3] - m[qt]);
        ls += (p0 + p1) + (p2 + p3);
        pf[tt][qt] = pack2(cvt_pk_bf16(p0, p1), cvt_pk_bf16(p2, p3));
      }
      l[qt] += ls;
    }

    // ---- PV: O^T += V^T @ P^T, A = V^T rows from LDS (shared by qt) ----
#pragma unroll
    for (int dt = 0; dt < 4; ++dt) {
#pragma unroll
      for (int tt = 0; tt < 4; ++tt) {
        short4 vf = *(const short4*)&Vs[dt * 16 + lq][tt * 16 + quad * 4];
#pragma unroll
        for (int qt = 0; qt < 2; ++qt)
          Oacc[dt][qt] = MFMA16(vf, pf[tt][qt], Oacc[dt][qt]);
      }
    }
  }

  // ---- epilogue ----
#pragma unroll
  for (int qt = 0; qt < 2; ++qt) {
    float lv = l[qt];
    lv += __shfl_xor(lv, 16, 64);
    lv += __shfl_xor(lv, 32, 64);
    const float inv = 1.f / lv;

    short* orow = O + ((size_t)(b * kS + q0 + wave * 32 + qt * 16 + lq)) * kE + h * kHD;
#pragma unroll
    for (int dt = 0; dt < 4; ++dt) {
      short4 o = pack2(cvt_pk_bf16(Oacc[dt][qt][0] * inv, Oacc[dt][qt][1] * inv),
                       cvt_pk_bf16(Oacc[dt][qt][2] * inv, Oacc[dt][qt][3] * inv));
      *(short4*)&orow[dt * 16 + quad * 4] = o;
    }
  }
}

}  // namespace

extern "C" void kernel_launch(void* const* d_in, const int* in_sizes, int n_in,
                              void* d_out, int out_size, void* d_ws, size_t ws_size,
                              hipStream_t stream) {
  // ---- workspace layout (bf16 shorts) ----
  short* ws = (short*)d_ws;
  short* Tq  = ws;                         // 1M each (lo outputs)
  short* Tk  = Tq  + (size_t)kM * kR;
  short* Tv  = Tk  + (size_t)kM * kR;
  short* Qh  = Tv  + (size_t)kM * kR;      // 4M each; head-major layouts
  short* Kh  = Qh  + (size_t)kM * kE;
  short* Vth = Kh  + (size_t)kM * kE;      // (B*H, 64, S)
  short* Ab  = Vth + (size_t)kM * kE;      // attn out bf16 (b,s,E)
  short* To  = Ab  + (size_t)kM * kE;      // 1M
  short* Wt  = To  + (size_t)kM * kR;      // 8 x 256K

  short* WtArr[8];
  for (int i = 0; i < 8; ++i) WtArr[i] = Wt + (size_t)i * (kE * kR);

  // ---- 1. weight transpose+convert ----
  PrepArgs pa;
  const int widx[8] = {3, 5, 7, 9, 11, 13, 15, 17};
  for (int i = 0; i < 8; ++i) { pa.src[i] = (const float*)d_in[widx[i]]; pa.dst[i] = WtArr[i]; }
  prep_weights<<<dim3(64, 8), dim3(256), 0, stream>>>(pa);

  // ---- 2. qkv lo GEMMs with fused fp32->bf16 A conversion ----
  {
    GemmLoArgs ga;
    ga.A[0] = (const float*)d_in[0]; ga.A[1] = (const float*)d_in[1]; ga.A[2] = (const float*)d_in[2];
    ga.Bt[0] = WtArr[0]; ga.Bt[1] = WtArr[2]; ga.Bt[2] = WtArr[4];
    ga.bias[0] = (const float*)d_in[4]; ga.bias[1] = (const float*)d_in[8]; ga.bias[2] = (const float*)d_in[12];
    ga.C[0] = Tq; ga.C[1] = Tk; ga.C[2] = Tv;
    gemm_lo_f32a<<<dim3(256, 3), dim3(256), 0, stream>>>(ga);
  }

  // ---- 3. qkv hi GEMMs -> attention layouts ----
  {
    GemmArgs ga;
    ga.A[0] = Tq; ga.A[1] = Tk; ga.A[2] = Tv;
    ga.Bt[0] = WtArr[1]; ga.Bt[1] = WtArr[3]; ga.Bt[2] = WtArr[5];
    ga.bias[0] = (const float*)d_in[6]; ga.bias[1] = (const float*)d_in[10]; ga.bias[2] = (const float*)d_in[14];
    ga.C[0] = Qh; ga.C[1] = Kh; ga.C[2] = Vth;
    // Q scale = 1/sqrt(HD) * log2(e): softmax runs in exp2/log2 domain.
    ga.scale[0] = 0.125f * 1.44269504088896340736f;
    ga.scale[1] = 1.f; ga.scale[2] = 1.f;
    gemm_bf16<kM, kE, kR, 128, 128, 1><<<dim3(256, 3), dim3(256), 0, stream>>>(ga);
  }

  // ---- 4. attention (128 q-rows per block) ----
  attn_mfma<<<dim3(kS / 128, kB * kH), dim3(256), 0, stream>>>(Qh, Kh, Vth, Ab);

  // ---- 5. output projection ----
  {
    GemmArgs ga;
    ga.A[0] = Ab; ga.Bt[0] = WtArr[6];
    ga.bias[0] = (const float*)d_in[16];
    ga.C[0] = To; ga.scale[0] = 1.f;
    gemm_bf16<kM, kR, kE, 64, 64, 0><<<dim3(256, 1), dim3(256), 0, stream>>>(ga);
  }
  {
    GemmArgs ga;
    ga.A[0] = To; ga.Bt[0] = WtArr[7];
    ga.bias[0] = (const float*)d_in[18];
    ga.C[0] = d_out; ga.scale[0] = 1.f;
    gemm_bf16<kM, kE, kR, 128, 128, 2><<<dim3(256, 1), dim3(256), 0, stream>>>(ga);
  }
}